// Round 18
// baseline (192.251 us; speedup 1.0000x reference)
//
#include <hip/hip_runtime.h>

// ---- static config (mirrors reference) ----
#define BB   2
#define NN   8192
#define KNN  40
#define SENT 8192
#define G0   17          // ceil coords for dl=0.06, pts in [0,1)
#define G1   9           // for dl=0.12
#define G0_3 (G0*G0*G0)  // 4913
#define G1_3 (G1*G1*G1)  // 729

// ball-query CSR grids: G = floor(1/r) so cell = 1/G >= r -> +-1 cells cover
#define GA   13          // r = 0.075  (conv0, pool0) supports = pts
#define GB   6           // r = 0.15   (up0, conv1, pool1) supports = pts1
#define GC   3           // r = 0.3    (up1, conv2) supports = pts2
#define GA_3 (GA*GA*GA)  // 2197
#define GB_3 (GB*GB*GB)  // 216
#define GC_3 (GC*GC*GC)  // 27

typedef unsigned long long ull;
typedef unsigned int       u32;
typedef unsigned short     u16;

// d2 exactly as numpy: (dx*dx + dy*dy) + dz*dz, no FMA contraction
__device__ __forceinline__ float sqdist(float qx, float qy, float qz,
                                        float sx, float sy, float sz) {
    float dx = __fsub_rn(qx, sx);
    float dy = __fsub_rn(qy, sy);
    float dz = __fsub_rn(qz, sz);
    return __fadd_rn(__fadd_rn(__fmul_rn(dx, dx), __fmul_rn(dy, dy)),
                     __fmul_rn(dz, dz));
}

// cell index for ball-query CSR (multiply form; only build/query consistency matters)
__device__ __forceinline__ int cell1(float p, float Gf, int G) {
    int c = (int)floorf(__fmul_rn(p, Gf));
    return min(max(c, 0), G - 1);
}
// cell coord for voxel subsample (DIVISION form — must mirror the reference)
__device__ __forceinline__ int vcell1(float p, float dlf, int G) {
    int c = (int)floorf(__fdiv_rn(p, dlf));
    return min(max(c, 0), G - 1);
}

// u64 cross-lane helpers (2x 32-bit shfl)
__device__ __forceinline__ ull shfl_u64(ull x, int src) {
    int lo = __shfl((int)(u32)x, src);
    int hi = __shfl((int)(u32)(x >> 32), src);
    return ((ull)(u32)hi << 32) | (ull)(u32)lo;
}
__device__ __forceinline__ ull shflxor_u64(ull x, int m) {
    int lo = __shfl_xor((int)(u32)x, m);
    int hi = __shfl_xor((int)(u32)(x >> 32), m);
    return ((ull)(u32)hi << 32) | (ull)(u32)lo;
}

// prep: copy pts -> out_points[0], SENTINEL fills, len[0]; + point-wise
// level-A histograms (csrA multiply-form + voxel0 division-form) via GLOBAL
// atomics into cnt arrays zeroed by the graph-head memset.  Same cell
// functions as the later scatter pass -> identical cells.
__global__ void prep_kernel(const float* __restrict__ pts, float* __restrict__ dout,
                            int* __restrict__ cntA, int* __restrict__ cntV0,
                            float dlf0) {
    const size_t PN = (size_t)BB * NN * 3;
    const size_t IN = (size_t)BB * NN * KNN;
    float* out_points0 = dout;
    float* out_pool2   = dout + 3 * PN + 3 * IN + 2 * IN;
    float* out_up2     = dout + 3 * PN + 6 * IN + 2 * IN;
    float* out_len     = dout + 3 * PN + 9 * IN;
    int i = blockIdx.x * 256 + threadIdx.x;
    if (i < (int)PN) out_points0[i] = pts[i];
    if (i < (int)IN) {
        out_pool2[i] = (float)SENT;
        out_up2[i]   = (float)SENT;
    }
    if (i < BB * NN) {                 // one thread per point: histograms
        int b = i >> 13;               // NN = 8192
        float px = pts[(size_t)i * 3], py = pts[(size_t)i * 3 + 1],
              pz = pts[(size_t)i * 3 + 2];
        const float Gf = (float)GA;
        int c = (cell1(px, Gf, GA) * GA + cell1(py, Gf, GA)) * GA + cell1(pz, Gf, GA);
        atomicAdd(&cntA[(size_t)b * GA_3 + c], 1);
        int cv = (vcell1(px, dlf0, G0) * G0 + vcell1(py, dlf0, G0)) * G0
                 + vcell1(pz, dlf0, G0);
        atomicAdd(&cntV0[(size_t)b * G0_3 + cv], 1);
    }
    if (i == 0) { out_len[0] = (float)NN; out_len[1] = (float)NN; }
}

// ---- CSR scan+scatter (histogram precomputed elsewhere) ----
// One 1024-thread block per batch.  Loads the global cnt arrays built by
// prep/means-hist (saving the serial histogram point-pass), then the proven
// scans + scatter.  CSR list stores PAYLOAD float4 {x,y,z,idx}.
// Scatter order within any cell is nondeterministic — harmless: ball-query
// top-40 is a set op; the means pass re-derives ascending order.
__global__ __launch_bounds__(1024) void scan_scatter(
    const float* __restrict__ pts, const int* __restrict__ len_ptr, int len_const,
    int G, int G3, const int* __restrict__ cntg,
    int* __restrict__ off, float4* __restrict__ lst4,
    float dlfv, int Gv, int G3v, const int* __restrict__ cntvg,
    int* __restrict__ offv, int* __restrict__ rankv,
    int* __restrict__ lstv, int* __restrict__ lenv_dev, float* __restrict__ lenv_out_f) {
    __shared__ int scnt[GA_3];    // CSR cells (max 2197)
    __shared__ int soff[GA_3];
    __shared__ int svcnt[G0_3];   // voxel cells (max 4913)
    __shared__ int svoff[G0_3];
    __shared__ int wsum[16];
    int b = blockIdx.x;
    int t = threadIdx.x;
    int len = len_ptr ? len_ptr[b] : len_const;
    const float* pb = pts + (size_t)b * NN * 3;
    float Gf = (float)G;
    bool dosub = Gv > 0;          // block-uniform
    for (int v = t; v < G3; v += 1024) scnt[v] = cntg[(size_t)b * G3 + v];
    if (dosub) for (int v = t; v < G3v; v += 1024) svcnt[v] = cntvg[(size_t)b * G3v + v];
    __syncthreads();
    int lane = t & 63, wid = t >> 6;
    // phase 2a: CSR exclusive scan -> soff + global off
    {
        int per = (G3 + 1023) >> 10;
        int start = t * per, end = min(start + per, G3);
        if (start > G3) start = G3;
        int csum = 0;
        for (int v = start; v < end; ++v) csum += scnt[v];
        int inc = csum;
        for (int d = 1; d < 64; d <<= 1) {
            int u = __shfl_up(inc, d);
            if (lane >= d) inc += u;
        }
        if (lane == 63) wsum[wid] = inc;
        __syncthreads();
        if (t < 16) {
            int wv = wsum[t];
            for (int d = 1; d < 16; d <<= 1) {
                int u = __shfl_up(wv, d);
                if (t >= d) wv += u;
            }
            wsum[t] = wv;
        }
        __syncthreads();
        int excl = inc - csum + (wid ? wsum[wid - 1] : 0);
        int run = excl;
        int* offb = off + (size_t)b * (G3 + 1);
        for (int v = start; v < end; ++v) {
            soff[v] = run;
            offb[v] = run;
            run += scnt[v];
        }
        if (t == 0) offb[G3] = len;
    }
    __syncthreads();               // wsum reuse fence
    // phase 2b: voxel packed scan (entries<<14 | occupied) -> svoff + globals
    if (dosub) {
        int per = (G3v + 1023) >> 10;
        int start = t * per, end = min(start + per, G3v);
        if (start > G3v) start = G3v;
        int ce = 0, co = 0;
        for (int v = start; v < end; ++v) { ce += svcnt[v]; co += (svcnt[v] > 0); }
        int pack = (ce << 14) | co;
        int inc = pack;
        for (int d = 1; d < 64; d <<= 1) {
            int u = __shfl_up(inc, d);
            if (lane >= d) inc += u;
        }
        if (lane == 63) wsum[wid] = inc;
        __syncthreads();
        if (t < 16) {
            int wv = wsum[t];
            for (int d = 1; d < 16; d <<= 1) {
                int u = __shfl_up(wv, d);
                if (t >= d) wv += u;
            }
            wsum[t] = wv;
        }
        __syncthreads();
        int excl = inc - pack + (wid ? wsum[wid - 1] : 0);
        int rune = excl >> 14;
        int runo = excl & 16383;
        int total = wsum[15] & 16383;
        int* offvb  = offv  + (size_t)b * (G3v + 1);
        int* rankvb = rankv + (size_t)b * G3v;
        for (int v = start; v < end; ++v) {
            svoff[v]  = rune;
            offvb[v]  = rune;
            rankvb[v] = runo;          // valid where occupied
            rune += svcnt[v];
            runo += (svcnt[v] > 0);
        }
        if (t == 0) {
            offvb[G3v] = len;
            lenv_dev[b] = total;
            lenv_out_f[b] = (float)total;
        }
    }
    __syncthreads();
    // phase 3: reset cursors, scatter both lists in one point pass
    for (int v = t; v < G3; v += 1024) scnt[v] = 0;
    if (dosub) for (int v = t; v < G3v; v += 1024) svcnt[v] = 0;
    __syncthreads();
    float4* lst4b = lst4 + (size_t)b * NN;
    int* lstvb = dosub ? (lstv + (size_t)b * NN) : nullptr;
    for (int i = t; i < len; i += 1024) {
        float px = pb[i * 3], py = pb[i * 3 + 1], pz = pb[i * 3 + 2];
        int c = (cell1(px, Gf, G) * G + cell1(py, Gf, G)) * G + cell1(pz, Gf, G);
        int pos = soff[c] + atomicAdd(&scnt[c], 1);
        lst4b[pos] = make_float4(px, py, pz, __int_as_float(i));
        if (dosub) {
            int cv = (vcell1(px, dlfv, Gv) * Gv + vcell1(py, dlfv, Gv)) * Gv
                     + vcell1(pz, dlfv, Gv);
            int posv = svoff[cv] + atomicAdd(&svcnt[cv], 1);
            lstvb[posv] = i;
        }
    }
}

// ---- fused ball-query (+ optional means z-slice), one WAVE per query ----
struct BqArgs {
    const float* q; const int* qlp; int qlc;
    const float4* lst; const int* off;
    int G; int G3; float r2; float* out;
};
struct MeansArgs {
    const float* pts; const int* off; const int* rnk; const int* lst;
    const int* len_dev; int G3; float* out;
    int Gc; int Gc3; int* cntc;           // next-level CSR hist (multiply form)
    float dlv; int Gv; int Gv3; int* cntv; // next-level voxel hist (Gv=0 -> none)
};

// Proven R16 bq body (MEASURED faster than R17's popc variant — the Batcher
// sort-8 hides under FILL latency as independent ILP, while popc-dependent
// masked writes sat on the fenced critical path): CSR 27-cell prune -> FILL
// (payload float4, slot skip) -> sort-8 compaction -> per-wave LDS staging
// -> adaptive bitonic sort -> bitonic merge with running top-40.
// blockIdx.z >= nbq runs the means slice (select-min-ascending + __frcp_rn,
// bit-identical) + next-level histograms from the exact written bits.
__global__ __launch_bounds__(256) void bq_fused(BqArgs pA, BqArgs pB, BqArgs pC,
                                                MeansArgs pM, int nbq) {
    const ull INITK = ~0ull;
    __shared__ ull wlds[4][512];   // per-wave chunk buffer, 16 KiB
    int z = blockIdx.z;
    if (z >= nbq) {                // ---- means slice (multi-block, parallel) ----
        int b = blockIdx.y;
        int i = blockIdx.x * 256 + threadIdx.x;
        if (i >= NN) return;       // G3 <= NN always
        const float* pb = pM.pts + (size_t)b * NN * 3;
        const int* offb = pM.off + (size_t)b * (pM.G3 + 1);
        const int* lstb = pM.lst + (size_t)b * NN;
        if (i < pM.G3) {
            int s = offb[i], e = offb[i + 1];
            int cn = e - s;
            if (cn > 0) {
                float sx = 0.f, sy = 0.f, sz = 0.f;
                int last = -1;
                for (int k = 0; k < cn; ++k) {           // select-min ascending
                    int m = 0x7FFFFFFF;
                    for (int j = s; j < e; ++j) {
                        int idx = lstb[j];
                        if (idx > last && idx < m) m = idx;
                    }
                    sx = __fadd_rn(sx, pb[m * 3]);
                    sy = __fadd_rn(sy, pb[m * 3 + 1]);
                    sz = __fadd_rn(sz, pb[m * 3 + 2]);
                    last = m;
                }
                float rinv = __frcp_rn((float)cn);       // EXACT (R14) — keep
                float mx = __fmul_rn(sx, rinv);
                float my = __fmul_rn(sy, rinv);
                float mz = __fmul_rn(sz, rinv);
                int rk = pM.rnk[(size_t)b * pM.G3 + i];
                float* op = pM.out + ((size_t)b * NN + rk) * 3;
                op[0] = mx; op[1] = my; op[2] = mz;
                // next-level histograms from the exact written bits
                float Gcf = (float)pM.Gc;
                int cc = (cell1(mx, Gcf, pM.Gc) * pM.Gc + cell1(my, Gcf, pM.Gc))
                         * pM.Gc + cell1(mz, Gcf, pM.Gc);
                atomicAdd(&pM.cntc[(size_t)b * pM.Gc3 + cc], 1);
                if (pM.Gv > 0) {
                    int cv = (vcell1(mx, pM.dlv, pM.Gv) * pM.Gv
                              + vcell1(my, pM.dlv, pM.Gv)) * pM.Gv
                             + vcell1(mz, pM.dlv, pM.Gv);
                    atomicAdd(&pM.cntv[(size_t)b * pM.Gv3 + cv], 1);
                }
            }
        }
        int total = pM.len_dev[b];
        if (i >= total) {                                // zero-pad tail rows
            float* op = pM.out + ((size_t)b * NN + i) * 3;
            op[0] = 0.f; op[1] = 0.f; op[2] = 0.f;
        }
        return;
    }
    const float* qpts   = z == 0 ? pA.q   : (z == 1 ? pB.q   : pC.q);
    const int* qlen_ptr = z == 0 ? pA.qlp : (z == 1 ? pB.qlp : pC.qlp);
    int qlen_const      = z == 0 ? pA.qlc : (z == 1 ? pB.qlc : pC.qlc);
    const float4* lst   = z == 0 ? pA.lst : (z == 1 ? pB.lst : pC.lst);
    const int* off      = z == 0 ? pA.off : (z == 1 ? pB.off : pC.off);
    int G               = z == 0 ? pA.G   : (z == 1 ? pB.G   : pC.G);
    int G3              = z == 0 ? pA.G3  : (z == 1 ? pB.G3  : pC.G3);
    float r2            = z == 0 ? pA.r2  : (z == 1 ? pB.r2  : pC.r2);
    float* out          = z == 0 ? pA.out : (z == 1 ? pB.out : pC.out);

    int t = threadIdx.x;
    int lane = t & 63;
    ull* wl = wlds[t >> 6];
    int b = blockIdx.y;
    int qi = blockIdx.x * 4 + (t >> 6);           // one wave per query
    int qlen = qlen_ptr ? qlen_ptr[b] : qlen_const;
    float* op = out + ((size_t)b * NN + qi) * KNN;
    if (qi >= qlen) {                             // wave-uniform
        if (lane < KNN) op[lane] = (float)SENT;
        return;
    }
    const float* qp = qpts + ((size_t)b * NN + qi) * 3;
    float qx = qp[0], qy = qp[1], qz = qp[2];
    float Gf = (float)G;
    int cx = cell1(qx, Gf, G), cy = cell1(qy, Gf, G), cz = cell1(qz, Gf, G);
    const int* offb = off + (size_t)b * (G3 + 1);
    const float4* lstb = lst + (size_t)b * NN;

    int cnt = 0, cst = 0;
    if (lane < 27) {
        int dz = lane % 3 - 1, dy = (lane / 3) % 3 - 1, dxx = lane / 9 - 1;
        int x = cx + dxx, y = cy + dy, zz = cz + dz;
        bool ok = ((unsigned)x < (unsigned)G) & ((unsigned)y < (unsigned)G)
                                              & ((unsigned)zz < (unsigned)G);
        int c = ok ? (x * G + y) * G + zz : 0;
        int s = ok ? offb[c] : 0;
        int e = ok ? offb[c + 1] : 0;
        cnt = e - s;
        cst = s;
    }
    int incl = cnt;
#pragma unroll
    for (int d_ = 1; d_ < 64; d_ <<= 1) {
        int u = __shfl_up(incl, d_);
        if (lane >= d_) incl += u;
    }
    int excl = incl - cnt;
    int T = __shfl(incl, 63);

    ull res = INITK;                              // lane k<40 holds k-th best
    bool have_res = false;
    for (int r0 = 0; r0 < T; r0 += 512) {
        ull c0 = INITK, c1 = INITK, c2 = INITK, c3 = INITK,
            c4 = INITK, c5 = INITK, c6 = INITK, c7 = INITK;
#define FILL(S, CS) if (r0 + (S) * 64 < T) {                                   \
            int g = r0 + (S) * 64 + lane;                                      \
            bool gok = g < T;                                                  \
            int gc = gok ? g : (T - 1);                                        \
            int d = 0;                                                         \
            if (__shfl(excl, d | 16) <= gc) d |= 16;                           \
            if (__shfl(excl, d | 8)  <= gc) d |= 8;                            \
            if (__shfl(excl, d | 4)  <= gc) d |= 4;                            \
            if (__shfl(excl, d | 2)  <= gc) d |= 2;                            \
            if (__shfl(excl, d | 1)  <= gc) d |= 1;                            \
            int st = __shfl(cst, d), eg = __shfl(excl, d);                     \
            float4 f = lstb[st + (gc - eg)];                                   \
            float d2 = sqdist(qx, qy, qz, f.x, f.y, f.z);                      \
            if (gok && d2 <= r2)                                               \
                CS = (((ull)__float_as_uint(d2)) << 13)                        \
                     | (ull)(u32)__float_as_int(f.w);                          \
        }
        FILL(0, c0) FILL(1, c1) FILL(2, c2) FILL(3, c3)
        FILL(4, c4) FILL(5, c5) FILL(6, c6) FILL(7, c7)
#undef FILL
        // per-lane Batcher sort-8 ascending (INITK sinks to back ->
        // valid keys compact at slots 0..m-1); hides under FILL latency
#define CE(A, B) { ull lo_ = (A < B) ? A : B; ull hi_ = (A < B) ? B : A; A = lo_; B = hi_; }
        CE(c0,c1) CE(c2,c3) CE(c4,c5) CE(c6,c7)
        CE(c0,c2) CE(c1,c3) CE(c4,c6) CE(c5,c7)
        CE(c1,c2) CE(c5,c6)
        CE(c0,c4) CE(c1,c5) CE(c2,c6) CE(c3,c7)
        CE(c2,c4) CE(c3,c5)
        CE(c1,c2) CE(c3,c4) CE(c5,c6)
#undef CE
        int m = (c0 != INITK) + (c1 != INITK) + (c2 != INITK) + (c3 != INITK)
              + (c4 != INITK) + (c5 != INITK) + (c6 != INITK) + (c7 != INITK);
        int incm = m;
#pragma unroll
        for (int d_ = 1; d_ < 64; d_ <<= 1) {
            int u = __shfl_up(incm, d_);
            if (lane >= d_) incm += u;
        }
        int base = incm - m;
        int M = __shfl(incm, 63);
        // WAR fence: previous chunk's wl reads complete before overwrite
        asm volatile("s_waitcnt lgkmcnt(0)" ::: "memory");
        __builtin_amdgcn_sched_barrier(0);
        if (m > 0) {
            wl[base] = c0;
            if (m > 1) wl[base + 1] = c1;
            if (m > 2) wl[base + 2] = c2;
            if (m > 3) wl[base + 3] = c3;
            if (m > 4) wl[base + 4] = c4;
            if (m > 5) wl[base + 5] = c5;
            if (m > 6) wl[base + 6] = c6;
            if (m > 7) wl[base + 7] = c7;
        }
        // RAW fence: writes drained before cross-lane reads
        asm volatile("s_waitcnt lgkmcnt(0)" ::: "memory");
        __builtin_amdgcn_sched_barrier(0);
        int npass = (M + 63) >> 6;                // wave-uniform
        for (int p = 0; p < npass; ++p) {
            int D = p * 64 + lane;
            ull key = (D < M) ? wl[D] : INITK;
            int mc = M - p * 64;                  // valid keys in chunk (uniform)
            // adaptive bitonic: stage k only if mc > k/2 (exact skip: after
            // stages <= k/2 all valid keys sorted in low lanes, INITK above
            // -> remaining merges identity)
#define BSTAGE(K) { _Pragma("unroll")                                          \
            for (int jj = (K) >> 1; jj > 0; jj >>= 1) {                        \
                ull other = shflxor_u64(key, jj);                              \
                bool up = ((lane & (K)) == 0);                                 \
                bool lowlane = ((lane & jj) == 0);                             \
                bool takeMin = (lowlane == up);                                \
                bool lt = key < other;                                         \
                key = (takeMin == lt) ? key : other;                           \
            } }
            if (mc > 1)  BSTAGE(2)
            if (mc > 2)  BSTAGE(4)
            if (mc > 4)  BSTAGE(8)
            if (mc > 8)  BSTAGE(16)
            if (mc > 16) BSTAGE(32)
            if (mc > 32) BSTAGE(64)
#undef BSTAGE
            if (!have_res) {
                res = key;
                have_res = true;
            } else {
                ull rb = shfl_u64(key, 63 - lane);    // reversed -> descending
                ull lo_ = (res < rb) ? res : rb;      // bitonic lower-64
#pragma unroll
                for (int jj = 32; jj > 0; jj >>= 1) { // cleanup -> sorted
                    ull other = shflxor_u64(lo_, jj);
                    bool lowlane = ((lane & jj) == 0);
                    bool lt = lo_ < other;
                    lo_ = (lowlane == lt) ? lo_ : other;
                }
                res = lo_;
            }
        }
    }
    if (lane < KNN)
        op[lane] = (res == INITK) ? (float)SENT : (float)(int)(res & 0x1FFFu);
}

extern "C" void kernel_launch(void* const* d_in, const int* in_sizes, int n_in,
                              void* d_out, int out_size, void* d_ws, size_t ws_size,
                              hipStream_t stream) {
    const float* pts = (const float*)d_in[0];
    float* dout = (float*)d_out;
    const size_t PN = (size_t)BB * NN * 3;     // 49152
    const size_t IN = (size_t)BB * NN * KNN;   // 655360
    float* out_points = dout;
    float* out_neigh  = dout + 3 * PN;
    float* out_pool   = out_neigh + 3 * IN;
    float* out_up     = out_pool + 3 * IN;
    float* out_len    = out_up + 3 * IN;
    float* pts1 = out_points + PN;       // layer-1 points live directly in d_out
    float* pts2 = out_points + 2 * PN;

    // workspace layout: float4 payload lists FIRST (16B alignment), then ints
    float4* lst4A = (float4*)d_ws;                           // BB*NN float4
    float4* lst4B = lst4A + (size_t)BB * NN;                 // BB*NN float4
    float4* lst4C = lst4B + (size_t)BB * NN;                 // BB*NN float4
    int*   len1  = (int*)(lst4C + (size_t)BB * NN);          // BB
    int*   len2  = len1 + BB;                                // BB
    int*   offV0 = len2 + BB;                                // BB*(G0_3+1)
    int*   rnk0  = offV0 + (size_t)BB * (G0_3 + 1);          // BB*G0_3
    int*   lstV0 = rnk0 + (size_t)BB * G0_3;                 // BB*NN
    int*   offV1 = lstV0 + (size_t)BB * NN;                  // BB*(G1_3+1)
    int*   rnk1  = offV1 + (size_t)BB * (G1_3 + 1);          // BB*G1_3
    int*   lstV1 = rnk1 + (size_t)BB * G1_3;                 // BB*NN
    int*   offA  = lstV1 + (size_t)BB * NN;                  // BB*(GA_3+1)
    int*   offB  = offA + (size_t)BB * (GA_3 + 1);           // BB*(GB_3+1)
    int*   offC  = offB + (size_t)BB * (GB_3 + 1);           // BB*(GC_3+1)
    // contiguous cnt block (zeroed by ONE memset at graph head)
    int*   cntA  = offC + (size_t)BB * (GC_3 + 1);           // BB*GA_3
    int*   cntV0 = cntA + (size_t)BB * GA_3;                 // BB*G0_3
    int*   cntB  = cntV0 + (size_t)BB * G0_3;                // BB*GB_3
    int*   cntV1 = cntB + (size_t)BB * GB_3;                 // BB*G1_3
    int*   cntC  = cntV1 + (size_t)BB * G1_3;                // BB*GC_3
    size_t cntBytes = (size_t)BB * (GA_3 + G0_3 + GB_3 + G1_3 + GC_3) * sizeof(int);

    // mirror Python double-precision scalar arithmetic, then narrow to f32
    double r_normal = 0.03 * 2.5;                 // 0.075
    double r0 = r_normal;
    double dl0 = 2.0 * r_normal / 2.5;            // 0.06
    float r2_0   = (float)(r0 * r0);
    float r2_up0 = (float)((2.0 * r0) * (2.0 * r0));
    float dlf0   = (float)dl0;
    r_normal *= 2.0;                              // 0.15
    double r1 = r_normal;
    double dl1 = 2.0 * r_normal / 2.5;            // 0.12
    float r2_1   = (float)(r1 * r1);
    float r2_up1 = (float)((2.0 * r1) * (2.0 * r1));
    float dlf1   = (float)dl1;
    r_normal *= 2.0;                              // 0.3
    float r2_2 = (float)(r_normal * r_normal);

    BqArgs conv0 = { pts,  nullptr, NN, lst4A, offA, GA, GA_3, r2_0,   out_neigh + 0 * IN };
    BqArgs pool0 = { pts1, len1,    0,  lst4A, offA, GA, GA_3, r2_0,   out_pool  + 0 * IN };
    BqArgs up0   = { pts,  nullptr, NN, lst4B, offB, GB, GB_3, r2_up0, out_up    + 0 * IN };
    BqArgs conv1 = { pts1, len1,    0,  lst4B, offB, GB, GB_3, r2_1,   out_neigh + 1 * IN };
    BqArgs pool1 = { pts2, len2,    0,  lst4B, offB, GB, GB_3, r2_1,   out_pool  + 1 * IN };
    BqArgs up1   = { pts1, len1,    0,  lst4C, offC, GC, GC_3, r2_up1, out_up    + 1 * IN };
    BqArgs conv2 = { pts2, len2,    0,  lst4C, offC, GC, GC_3, r2_2,   out_neigh + 2 * IN };
    MeansArgs means0 = { pts,  offV0, rnk0, lstV0, len1, G0_3, pts1,
                         GB, GB_3, cntB, dlf1, G1, G1_3, cntV1 };
    MeansArgs means1 = { pts1, offV1, rnk1, lstV1, len2, G1_3, pts2,
                         GC, GC_3, cntC, 0.f, 0, 0, nullptr };

    dim3 gD1(NN / 4, BB, 2);   // conv0 + means0 slice
    dim3 gD2(NN / 4, BB, 4);   // pool0, up0, conv1 + means1 slice
    dim3 gD3(NN / 4, BB, 3);   // pool1, up1, conv2

    // zero histogram counters (poison-safe), then histograms ride in
    // parallel kernels via global atomics
    hipMemsetAsync(cntA, 0, cntBytes, stream);
    prep_kernel<<<(int)((IN + 255) / 256), 256, 0, stream>>>(pts, dout, cntA,
                                                             cntV0, dlf0);
    // CSR_A scan+scatter (+ level-0 voxel)
    scan_scatter<<<BB, 1024, 0, stream>>>(pts, nullptr, NN, GA, GA_3, cntA,
                                          offA, lst4A, dlf0, G0, G0_3, cntV0,
                                          offV0, rnk0, lstV0, len1, out_len + 2);
    // D1: conv0  ∥  means0 -> pts1 (+histB, +histV1)
    bq_fused<<<gD1, 256, 0, stream>>>(conv0, conv0, conv0, means0, 1);
    // CSR_B scan+scatter (+ level-1 voxel)
    scan_scatter<<<BB, 1024, 0, stream>>>(pts1, len1, 0, GB, GB_3, cntB,
                                          offB, lst4B, dlf1, G1, G1_3, cntV1,
                                          offV1, rnk1, lstV1, len2, out_len + 4);
    // D2: pool0, up0, conv1  ∥  means1 -> pts2 (+histC)
    bq_fused<<<gD2, 256, 0, stream>>>(pool0, up0, conv1, means1, 3);
    // CSR_C scan+scatter (no voxel work)
    scan_scatter<<<BB, 1024, 0, stream>>>(pts2, len2, 0, GC, GC_3, cntC,
                                          offC, lst4C, 0.f, 0, 0, nullptr,
                                          nullptr, nullptr, nullptr, nullptr,
                                          nullptr);
    // D3: pool1, up1, conv2
    bq_fused<<<gD3, 256, 0, stream>>>(pool1, up1, conv2, means1, 3);
}

// Round 19
// 178.828 us; speedup vs baseline: 1.0751x; 1.0751x over previous
//
#include <hip/hip_runtime.h>

// ---- static config (mirrors reference) ----
#define BB   2
#define NN   8192
#define KNN  40
#define SENT 8192
#define G0   17          // ceil coords for dl=0.06, pts in [0,1)
#define G1   9           // for dl=0.12
#define G0_3 (G0*G0*G0)  // 4913
#define G1_3 (G1*G1*G1)  // 729

// ball-query CSR grids: G = floor(1/r) so cell = 1/G >= r -> +-1 cells cover
#define GA   13          // r = 0.075  (conv0, pool0) supports = pts
#define GB   6           // r = 0.15   (up0, conv1, pool1) supports = pts1
#define GC   3           // r = 0.3    (up1, conv2) supports = pts2
#define GA_3 (GA*GA*GA)  // 2197
#define GB_3 (GB*GB*GB)  // 216
#define GC_3 (GC*GC*GC)  // 27

typedef unsigned long long ull;
typedef unsigned int       u32;
typedef unsigned short     u16;

// d2 exactly as numpy: (dx*dx + dy*dy) + dz*dz, no FMA contraction
__device__ __forceinline__ float sqdist(float qx, float qy, float qz,
                                        float sx, float sy, float sz) {
    float dx = __fsub_rn(qx, sx);
    float dy = __fsub_rn(qy, sy);
    float dz = __fsub_rn(qz, sz);
    return __fadd_rn(__fadd_rn(__fmul_rn(dx, dx), __fmul_rn(dy, dy)),
                     __fmul_rn(dz, dz));
}

// cell index for ball-query CSR (multiply form; only build/query consistency matters)
__device__ __forceinline__ int cell1(float p, float Gf, int G) {
    int c = (int)floorf(__fmul_rn(p, Gf));
    return min(max(c, 0), G - 1);
}
// cell coord for voxel subsample (DIVISION form — must mirror the reference)
__device__ __forceinline__ int vcell1(float p, float dlf, int G) {
    int c = (int)floorf(__fdiv_rn(p, dlf));
    return min(max(c, 0), G - 1);
}

// u64 cross-lane helpers (2x 32-bit shfl)
__device__ __forceinline__ ull shfl_u64(ull x, int src) {
    int lo = __shfl((int)(u32)x, src);
    int hi = __shfl((int)(u32)(x >> 32), src);
    return ((ull)(u32)hi << 32) | (ull)(u32)lo;
}
__device__ __forceinline__ ull shflxor_u64(ull x, int m) {
    int lo = __shfl_xor((int)(u32)x, m);
    int hi = __shfl_xor((int)(u32)(x >> 32), m);
    return ((ull)(u32)hi << 32) | (ull)(u32)lo;
}

// prep: copy pts -> out_points[0], fill layer-2 pool/up with SENTINEL, len[0]
__global__ void prep_kernel(const float* __restrict__ pts, float* __restrict__ dout) {
    const size_t PN = (size_t)BB * NN * 3;
    const size_t IN = (size_t)BB * NN * KNN;
    float* out_points0 = dout;
    float* out_pool2   = dout + 3 * PN + 3 * IN + 2 * IN;
    float* out_up2     = dout + 3 * PN + 6 * IN + 2 * IN;
    float* out_len     = dout + 3 * PN + 9 * IN;
    int i = blockIdx.x * 256 + threadIdx.x;
    if (i < (int)PN) out_points0[i] = pts[i];
    if (i < (int)IN) {
        out_pool2[i] = (float)SENT;
        out_up2[i]   = (float)SENT;
    }
    if (i == 0) { out_len[0] = (float)NN; out_len[1] = (float)NN; }
}

// ---- CSR build over supports + fused voxel-grid subsample prep ----
// One 1024-thread block per batch.  CSR list stores PAYLOAD float4
// {x, y, z, bitcast(idx)} so bq's FILL does one 16B load per candidate
// (coords are exact bit copies -> identical keys).  Voxel list stays
// index-form for the means pass.  Scatter order within any cell is
// nondeterministic (LDS atomics) — harmless: ball-query top-40 is a set op;
// the means pass re-derives ascending order.
// NOTE (R19): histogram-offload to prep/means (R17/R18) measured SLOWER than
// this in-kernel histogram form — do not re-attempt without isolated A/B.
__global__ __launch_bounds__(1024) void csr_build(
    const float* __restrict__ pts, const int* __restrict__ len_ptr, int len_const,
    int G, int G3, int* __restrict__ off, float4* __restrict__ lst4,
    float dlfv, int Gv, int G3v, int* __restrict__ offv, int* __restrict__ rankv,
    int* __restrict__ lstv, int* __restrict__ lenv_dev, float* __restrict__ lenv_out_f) {
    __shared__ int scnt[GA_3];    // CSR cells (max 2197)
    __shared__ int soff[GA_3];
    __shared__ int svcnt[G0_3];   // voxel cells (max 4913)
    __shared__ int svoff[G0_3];
    __shared__ int wsum[16];
    int b = blockIdx.x;
    int t = threadIdx.x;
    int len = len_ptr ? len_ptr[b] : len_const;
    const float* pb = pts + (size_t)b * NN * 3;
    float Gf = (float)G;
    bool dosub = Gv > 0;          // block-uniform
    for (int v = t; v < G3; v += 1024) scnt[v] = 0;
    if (dosub) for (int v = t; v < G3v; v += 1024) svcnt[v] = 0;
    __syncthreads();
    // phase 1: both histograms in one point pass
    for (int i = t; i < len; i += 1024) {
        float px = pb[i * 3], py = pb[i * 3 + 1], pz = pb[i * 3 + 2];
        int c = (cell1(px, Gf, G) * G + cell1(py, Gf, G)) * G + cell1(pz, Gf, G);
        atomicAdd(&scnt[c], 1);
        if (dosub) {
            int cv = (vcell1(px, dlfv, Gv) * Gv + vcell1(py, dlfv, Gv)) * Gv
                     + vcell1(pz, dlfv, Gv);
            atomicAdd(&svcnt[cv], 1);
        }
    }
    __syncthreads();
    int lane = t & 63, wid = t >> 6;
    // phase 2a: CSR exclusive scan -> soff + global off
    {
        int per = (G3 + 1023) >> 10;
        int start = t * per, end = min(start + per, G3);
        if (start > G3) start = G3;
        int csum = 0;
        for (int v = start; v < end; ++v) csum += scnt[v];
        int inc = csum;
        for (int d = 1; d < 64; d <<= 1) {
            int u = __shfl_up(inc, d);
            if (lane >= d) inc += u;
        }
        if (lane == 63) wsum[wid] = inc;
        __syncthreads();
        if (t < 16) {
            int wv = wsum[t];
            for (int d = 1; d < 16; d <<= 1) {
                int u = __shfl_up(wv, d);
                if (t >= d) wv += u;
            }
            wsum[t] = wv;
        }
        __syncthreads();
        int excl = inc - csum + (wid ? wsum[wid - 1] : 0);
        int run = excl;
        int* offb = off + (size_t)b * (G3 + 1);
        for (int v = start; v < end; ++v) {
            soff[v] = run;
            offb[v] = run;
            run += scnt[v];
        }
        if (t == 0) offb[G3] = len;
    }
    __syncthreads();               // wsum reuse fence
    // phase 2b: voxel packed scan (entries<<14 | occupied) -> svoff + globals
    if (dosub) {
        int per = (G3v + 1023) >> 10;
        int start = t * per, end = min(start + per, G3v);
        if (start > G3v) start = G3v;
        int ce = 0, co = 0;
        for (int v = start; v < end; ++v) { ce += svcnt[v]; co += (svcnt[v] > 0); }
        int pack = (ce << 14) | co;
        int inc = pack;
        for (int d = 1; d < 64; d <<= 1) {
            int u = __shfl_up(inc, d);
            if (lane >= d) inc += u;
        }
        if (lane == 63) wsum[wid] = inc;
        __syncthreads();
        if (t < 16) {
            int wv = wsum[t];
            for (int d = 1; d < 16; d <<= 1) {
                int u = __shfl_up(wv, d);
                if (t >= d) wv += u;
            }
            wsum[t] = wv;
        }
        __syncthreads();
        int excl = inc - pack + (wid ? wsum[wid - 1] : 0);
        int rune = excl >> 14;
        int runo = excl & 16383;
        int total = wsum[15] & 16383;
        int* offvb  = offv  + (size_t)b * (G3v + 1);
        int* rankvb = rankv + (size_t)b * G3v;
        for (int v = start; v < end; ++v) {
            svoff[v]  = rune;
            offvb[v]  = rune;
            rankvb[v] = runo;          // valid where occupied
            rune += svcnt[v];
            runo += (svcnt[v] > 0);
        }
        if (t == 0) {
            offvb[G3v] = len;
            lenv_dev[b] = total;
            lenv_out_f[b] = (float)total;
        }
    }
    __syncthreads();
    // phase 3: reset cursors, scatter both lists in one point pass
    for (int v = t; v < G3; v += 1024) scnt[v] = 0;
    if (dosub) for (int v = t; v < G3v; v += 1024) svcnt[v] = 0;
    __syncthreads();
    float4* lst4b = lst4 + (size_t)b * NN;
    int* lstvb = dosub ? (lstv + (size_t)b * NN) : nullptr;
    for (int i = t; i < len; i += 1024) {
        float px = pb[i * 3], py = pb[i * 3 + 1], pz = pb[i * 3 + 2];
        int c = (cell1(px, Gf, G) * G + cell1(py, Gf, G)) * G + cell1(pz, Gf, G);
        int pos = soff[c] + atomicAdd(&scnt[c], 1);
        lst4b[pos] = make_float4(px, py, pz, __int_as_float(i));
        if (dosub) {
            int cv = (vcell1(px, dlfv, Gv) * Gv + vcell1(py, dlfv, Gv)) * Gv
                     + vcell1(pz, dlfv, Gv);
            int posv = svoff[cv] + atomicAdd(&svcnt[cv], 1);
            lstvb[posv] = i;
        }
    }
}

// ---- fused ball-query (+ optional means z-slice), one WAVE per query ----
struct BqArgs {
    const float* q; const int* qlp; int qlc;
    const float4* lst; const int* off;
    int G; int G3; float r2; float* out;
};
struct MeansArgs {
    const float* pts; const int* off; const int* rnk; const int* lst;
    const int* len_dev; int G3; float* out;
};

// Proven bq body: CSR 27-cell prune -> FILL (payload float4, slot skip) ->
// Batcher sort-8 (hides under FILL latency) -> per-wave LDS staging ->
// adaptive bitonic sort -> bitonic merge with running top-40.
// blockIdx.z >= nbq runs the means slice (select-min-ascending summation ==
// reference stable segment_sum association -> bit-identical; __frcp_rn mean
// R14-verified EXACT — DO NOT change to true division), so independent means
// work rides along with bq in ONE dispatch.  Adaptive bitonic: stage k only
// when mc > k/2 — if mc <= k/2 all valid keys are already sorted in lanes
// 0..k/2-1 with INITK above -> remaining merges identity -> exact skip.
__global__ __launch_bounds__(256) void bq_fused(BqArgs pA, BqArgs pB, BqArgs pC,
                                                MeansArgs pM, int nbq) {
    const ull INITK = ~0ull;
    __shared__ ull wlds[4][512];   // per-wave chunk buffer, 16 KiB
    int z = blockIdx.z;
    if (z >= nbq) {                // ---- means slice (multi-block, parallel) ----
        int b = blockIdx.y;
        int i = blockIdx.x * 256 + threadIdx.x;
        if (i >= NN) return;       // G3 <= NN always
        const float* pb = pM.pts + (size_t)b * NN * 3;
        const int* offb = pM.off + (size_t)b * (pM.G3 + 1);
        const int* lstb = pM.lst + (size_t)b * NN;
        if (i < pM.G3) {
            int s = offb[i], e = offb[i + 1];
            int cn = e - s;
            if (cn > 0) {
                float sx = 0.f, sy = 0.f, sz = 0.f;
                int last = -1;
                for (int k = 0; k < cn; ++k) {           // select-min ascending
                    int m = 0x7FFFFFFF;
                    for (int j = s; j < e; ++j) {
                        int idx = lstb[j];
                        if (idx > last && idx < m) m = idx;
                    }
                    sx = __fadd_rn(sx, pb[m * 3]);
                    sy = __fadd_rn(sy, pb[m * 3 + 1]);
                    sz = __fadd_rn(sz, pb[m * 3 + 2]);
                    last = m;
                }
                float rinv = __frcp_rn((float)cn);       // EXACT (R14) — keep
                int rk = pM.rnk[(size_t)b * pM.G3 + i];
                float* op = pM.out + ((size_t)b * NN + rk) * 3;
                op[0] = __fmul_rn(sx, rinv);
                op[1] = __fmul_rn(sy, rinv);
                op[2] = __fmul_rn(sz, rinv);
            }
        }
        int total = pM.len_dev[blockIdx.y];
        if (i >= total) {                                // zero-pad tail rows
            float* op = pM.out + ((size_t)blockIdx.y * NN + i) * 3;
            op[0] = 0.f; op[1] = 0.f; op[2] = 0.f;
        }
        return;
    }
    const float* qpts   = z == 0 ? pA.q   : (z == 1 ? pB.q   : pC.q);
    const int* qlen_ptr = z == 0 ? pA.qlp : (z == 1 ? pB.qlp : pC.qlp);
    int qlen_const      = z == 0 ? pA.qlc : (z == 1 ? pB.qlc : pC.qlc);
    const float4* lst   = z == 0 ? pA.lst : (z == 1 ? pB.lst : pC.lst);
    const int* off      = z == 0 ? pA.off : (z == 1 ? pB.off : pC.off);
    int G               = z == 0 ? pA.G   : (z == 1 ? pB.G   : pC.G);
    int G3              = z == 0 ? pA.G3  : (z == 1 ? pB.G3  : pC.G3);
    float r2            = z == 0 ? pA.r2  : (z == 1 ? pB.r2  : pC.r2);
    float* out          = z == 0 ? pA.out : (z == 1 ? pB.out : pC.out);

    int t = threadIdx.x;
    int lane = t & 63;
    ull* wl = wlds[t >> 6];
    int b = blockIdx.y;
    int qi = blockIdx.x * 4 + (t >> 6);           // one wave per query
    int qlen = qlen_ptr ? qlen_ptr[b] : qlen_const;
    float* op = out + ((size_t)b * NN + qi) * KNN;
    if (qi >= qlen) {                             // wave-uniform
        if (lane < KNN) op[lane] = (float)SENT;
        return;
    }
    const float* qp = qpts + ((size_t)b * NN + qi) * 3;
    float qx = qp[0], qy = qp[1], qz = qp[2];
    float Gf = (float)G;
    int cx = cell1(qx, Gf, G), cy = cell1(qy, Gf, G), cz = cell1(qz, Gf, G);
    const int* offb = off + (size_t)b * (G3 + 1);
    const float4* lstb = lst + (size_t)b * NN;

    int cnt = 0, cst = 0;
    if (lane < 27) {
        int dz = lane % 3 - 1, dy = (lane / 3) % 3 - 1, dxx = lane / 9 - 1;
        int x = cx + dxx, y = cy + dy, zz = cz + dz;
        bool ok = ((unsigned)x < (unsigned)G) & ((unsigned)y < (unsigned)G)
                                              & ((unsigned)zz < (unsigned)G);
        int c = ok ? (x * G + y) * G + zz : 0;
        int s = ok ? offb[c] : 0;
        int e = ok ? offb[c + 1] : 0;
        cnt = e - s;
        cst = s;
    }
    int incl = cnt;
#pragma unroll
    for (int d_ = 1; d_ < 64; d_ <<= 1) {
        int u = __shfl_up(incl, d_);
        if (lane >= d_) incl += u;
    }
    int excl = incl - cnt;
    int T = __shfl(incl, 63);

    ull res = INITK;                              // lane k<40 holds k-th best
    bool have_res = false;
    for (int r0 = 0; r0 < T; r0 += 512) {
        ull c0 = INITK, c1 = INITK, c2 = INITK, c3 = INITK,
            c4 = INITK, c5 = INITK, c6 = INITK, c7 = INITK;
#define FILL(S, CS) if (r0 + (S) * 64 < T) {                                   \
            int g = r0 + (S) * 64 + lane;                                      \
            bool gok = g < T;                                                  \
            int gc = gok ? g : (T - 1);                                        \
            int d = 0;                                                         \
            if (__shfl(excl, d | 16) <= gc) d |= 16;                           \
            if (__shfl(excl, d | 8)  <= gc) d |= 8;                            \
            if (__shfl(excl, d | 4)  <= gc) d |= 4;                            \
            if (__shfl(excl, d | 2)  <= gc) d |= 2;                            \
            if (__shfl(excl, d | 1)  <= gc) d |= 1;                            \
            int st = __shfl(cst, d), eg = __shfl(excl, d);                     \
            float4 f = lstb[st + (gc - eg)];                                   \
            float d2 = sqdist(qx, qy, qz, f.x, f.y, f.z);                      \
            if (gok && d2 <= r2)                                               \
                CS = (((ull)__float_as_uint(d2)) << 13)                        \
                     | (ull)(u32)__float_as_int(f.w);                          \
        }
        FILL(0, c0) FILL(1, c1) FILL(2, c2) FILL(3, c3)
        FILL(4, c4) FILL(5, c5) FILL(6, c6) FILL(7, c7)
#undef FILL
        // per-lane Batcher sort-8 ascending (INITK sinks to back ->
        // valid keys compact at slots 0..m-1)
#define CE(A, B) { ull lo_ = (A < B) ? A : B; ull hi_ = (A < B) ? B : A; A = lo_; B = hi_; }
        CE(c0,c1) CE(c2,c3) CE(c4,c5) CE(c6,c7)
        CE(c0,c2) CE(c1,c3) CE(c4,c6) CE(c5,c7)
        CE(c1,c2) CE(c5,c6)
        CE(c0,c4) CE(c1,c5) CE(c2,c6) CE(c3,c7)
        CE(c2,c4) CE(c3,c5)
        CE(c1,c2) CE(c3,c4) CE(c5,c6)
#undef CE
        int m = (c0 != INITK) + (c1 != INITK) + (c2 != INITK) + (c3 != INITK)
              + (c4 != INITK) + (c5 != INITK) + (c6 != INITK) + (c7 != INITK);
        int incm = m;
#pragma unroll
        for (int d_ = 1; d_ < 64; d_ <<= 1) {
            int u = __shfl_up(incm, d_);
            if (lane >= d_) incm += u;
        }
        int base = incm - m;
        int M = __shfl(incm, 63);
        // WAR fence: previous chunk's wl reads complete before overwrite
        asm volatile("s_waitcnt lgkmcnt(0)" ::: "memory");
        __builtin_amdgcn_sched_barrier(0);
        if (m > 0) {
            wl[base] = c0;
            if (m > 1) wl[base + 1] = c1;
            if (m > 2) wl[base + 2] = c2;
            if (m > 3) wl[base + 3] = c3;
            if (m > 4) wl[base + 4] = c4;
            if (m > 5) wl[base + 5] = c5;
            if (m > 6) wl[base + 6] = c6;
            if (m > 7) wl[base + 7] = c7;
        }
        // RAW fence: writes drained before cross-lane reads
        asm volatile("s_waitcnt lgkmcnt(0)" ::: "memory");
        __builtin_amdgcn_sched_barrier(0);
        int npass = (M + 63) >> 6;                // wave-uniform
        for (int p = 0; p < npass; ++p) {
            int D = p * 64 + lane;
            ull key = (D < M) ? wl[D] : INITK;
            int mc = M - p * 64;                  // valid keys in chunk (uniform)
            // adaptive bitonic: stage k only if mc > k/2 (exact skip)
#define BSTAGE(K) { _Pragma("unroll")                                          \
            for (int jj = (K) >> 1; jj > 0; jj >>= 1) {                        \
                ull other = shflxor_u64(key, jj);                              \
                bool up = ((lane & (K)) == 0);                                 \
                bool lowlane = ((lane & jj) == 0);                             \
                bool takeMin = (lowlane == up);                                \
                bool lt = key < other;                                         \
                key = (takeMin == lt) ? key : other;                           \
            } }
            if (mc > 1)  BSTAGE(2)
            if (mc > 2)  BSTAGE(4)
            if (mc > 4)  BSTAGE(8)
            if (mc > 8)  BSTAGE(16)
            if (mc > 16) BSTAGE(32)
            if (mc > 32) BSTAGE(64)
#undef BSTAGE
            if (!have_res) {
                res = key;
                have_res = true;
            } else {
                ull rb = shfl_u64(key, 63 - lane);    // reversed -> descending
                ull lo_ = (res < rb) ? res : rb;      // bitonic lower-64
#pragma unroll
                for (int jj = 32; jj > 0; jj >>= 1) { // cleanup -> sorted
                    ull other = shflxor_u64(lo_, jj);
                    bool lowlane = ((lane & jj) == 0);
                    bool lt = lo_ < other;
                    lo_ = (lowlane == lt) ? lo_ : other;
                }
                res = lo_;
            }
        }
    }
    if (lane < KNN)
        op[lane] = (res == INITK) ? (float)SENT : (float)(int)(res & 0x1FFFu);
}

extern "C" void kernel_launch(void* const* d_in, const int* in_sizes, int n_in,
                              void* d_out, int out_size, void* d_ws, size_t ws_size,
                              hipStream_t stream) {
    const float* pts = (const float*)d_in[0];
    float* dout = (float*)d_out;
    const size_t PN = (size_t)BB * NN * 3;     // 49152
    const size_t IN = (size_t)BB * NN * KNN;   // 655360
    float* out_points = dout;
    float* out_neigh  = dout + 3 * PN;
    float* out_pool   = out_neigh + 3 * IN;
    float* out_up     = out_pool + 3 * IN;
    float* out_len    = out_up + 3 * IN;
    float* pts1 = out_points + PN;       // layer-1 points live directly in d_out
    float* pts2 = out_points + 2 * PN;

    // workspace layout: float4 payload lists FIRST (16B alignment), then ints
    float4* lst4A = (float4*)d_ws;                           // BB*NN float4
    float4* lst4B = lst4A + (size_t)BB * NN;                 // BB*NN float4
    float4* lst4C = lst4B + (size_t)BB * NN;                 // BB*NN float4
    int*   len1  = (int*)(lst4C + (size_t)BB * NN);          // BB
    int*   len2  = len1 + BB;                                // BB
    int*   offV0 = len2 + BB;                                // BB*(G0_3+1)
    int*   rnk0  = offV0 + (size_t)BB * (G0_3 + 1);          // BB*G0_3
    int*   lstV0 = rnk0 + (size_t)BB * G0_3;                 // BB*NN
    int*   offV1 = lstV0 + (size_t)BB * NN;                  // BB*(G1_3+1)
    int*   rnk1  = offV1 + (size_t)BB * (G1_3 + 1);          // BB*G1_3
    int*   lstV1 = rnk1 + (size_t)BB * G1_3;                 // BB*NN
    int*   offA  = lstV1 + (size_t)BB * NN;                  // BB*(GA_3+1)
    int*   offB  = offA + (size_t)BB * (GA_3 + 1);           // BB*(GB_3+1)
    int*   offC  = offB + (size_t)BB * (GB_3 + 1);           // BB*(GC_3+1)

    // mirror Python double-precision scalar arithmetic, then narrow to f32
    double r_normal = 0.03 * 2.5;                 // 0.075
    double r0 = r_normal;
    double dl0 = 2.0 * r_normal / 2.5;            // 0.06
    float r2_0   = (float)(r0 * r0);
    float r2_up0 = (float)((2.0 * r0) * (2.0 * r0));
    float dlf0   = (float)dl0;
    r_normal *= 2.0;                              // 0.15
    double r1 = r_normal;
    double dl1 = 2.0 * r_normal / 2.5;            // 0.12
    float r2_1   = (float)(r1 * r1);
    float r2_up1 = (float)((2.0 * r1) * (2.0 * r1));
    float dlf1   = (float)dl1;
    r_normal *= 2.0;                              // 0.3
    float r2_2 = (float)(r_normal * r_normal);

    BqArgs conv0 = { pts,  nullptr, NN, lst4A, offA, GA, GA_3, r2_0,   out_neigh + 0 * IN };
    BqArgs pool0 = { pts1, len1,    0,  lst4A, offA, GA, GA_3, r2_0,   out_pool  + 0 * IN };
    BqArgs up0   = { pts,  nullptr, NN, lst4B, offB, GB, GB_3, r2_up0, out_up    + 0 * IN };
    BqArgs conv1 = { pts1, len1,    0,  lst4B, offB, GB, GB_3, r2_1,   out_neigh + 1 * IN };
    BqArgs pool1 = { pts2, len2,    0,  lst4B, offB, GB, GB_3, r2_1,   out_pool  + 1 * IN };
    BqArgs up1   = { pts1, len1,    0,  lst4C, offC, GC, GC_3, r2_up1, out_up    + 1 * IN };
    BqArgs conv2 = { pts2, len2,    0,  lst4C, offC, GC, GC_3, r2_2,   out_neigh + 2 * IN };
    MeansArgs means0 = { pts,  offV0, rnk0, lstV0, len1, G0_3, pts1 };
    MeansArgs means1 = { pts1, offV1, rnk1, lstV1, len2, G1_3, pts2 };

    dim3 gD1(NN / 4, BB, 2);   // conv0 + means0 slice
    dim3 gD2(NN / 4, BB, 4);   // pool0, up0, conv1 + means1 slice
    dim3 gD3(NN / 4, BB, 3);   // pool1, up1, conv2

    prep_kernel<<<(int)((IN + 255) / 256), 256, 0, stream>>>(pts, dout);
    // CSR_A (supports=pts, G=13) + level-0 voxel scan/scatter
    csr_build<<<BB, 1024, 0, stream>>>(pts, nullptr, NN, GA, GA_3, offA, lst4A,
                                       dlf0, G0, G0_3, offV0, rnk0, lstV0,
                                       len1, out_len + 2);
    // D1: conv0 (needs csrA only)  ∥  means0 -> pts1 (needs csrA only)
    bq_fused<<<gD1, 256, 0, stream>>>(conv0, conv0, conv0, means0, 1);
    // CSR_B (supports=pts1, G=6) + level-1 voxel scan/scatter
    csr_build<<<BB, 1024, 0, stream>>>(pts1, len1, 0, GB, GB_3, offB, lst4B,
                                       dlf1, G1, G1_3, offV1, rnk1, lstV1,
                                       len2, out_len + 4);
    // D2: pool0, up0, conv1 (need <= csrB)  ∥  means1 -> pts2 (needs csrB)
    bq_fused<<<gD2, 256, 0, stream>>>(pool0, up0, conv1, means1, 3);
    // CSR_C (supports=pts2, G=3), no voxel work
    csr_build<<<BB, 1024, 0, stream>>>(pts2, len2, 0, GC, GC_3, offC, lst4C,
                                       0.f, 0, 0, nullptr, nullptr, nullptr,
                                       nullptr, nullptr);
    // D3: pool1, up1, conv2
    bq_fused<<<gD3, 256, 0, stream>>>(pool1, up1, conv2, means1, 3);
}